// Round 1
// baseline (115.864 us; speedup 1.0000x reference)
//
#include <hip/hip_runtime.h>

#define NN 4096
#define BB 8
#define F_IN 40
#define HH 64
#define KW 5
#define LL (NN - KW + 1)   // 4092
#define RC 32              // row chunks for A passes
#define CHUNK (NN / RC)    // 128
#define COLB (NN / 256)    // 16
#define PC 16              // p-chunks for x contraction
#define PCH (NN / PC)      // 256

// workspace layout (in floats)
#define OFF_P1 0                          // [RC][NN]      partial colsums
#define OFF_C (OFF_P1 + RC * NN)          // [NN]          colsums c
#define OFF_P2 (OFF_C + NN)               // [RC][9][NN]   partial d/e vectors
#define OFF_D (OFF_P2 + RC * 9 * NN)      // [9][NN]       d, e_0..e_7
#define OFF_Q (OFF_D + 9 * NN)            // [BB][PC][9][F_IN] partial q
// total = 1,397,760 floats = 5.6 MB

__device__ __forceinline__ int special_row(int s) { return s < 4 ? s : (NN - 8 + s); }

// Pass 1 over A: partial column sums. grid (COLB, RC), block 256
__global__ void k1_colsum_part(const float* __restrict__ A, float* __restrict__ part1) {
    int col = blockIdx.x * 256 + threadIdx.x;
    int n0 = blockIdx.y * CHUNK;
    const float* Ap = A + (size_t)n0 * NN + col;
    float s = 0.f;
    #pragma unroll 4
    for (int j = 0; j < CHUNK; ++j) s += Ap[(size_t)j * NN];
    part1[(size_t)blockIdx.y * NN + col] = s;
}

// reduce partial colsums -> c. grid COLB, block 256
__global__ void k1_colsum_red(const float* __restrict__ part1, float* __restrict__ c) {
    int col = blockIdx.x * 256 + threadIdx.x;
    float s = 0.f;
    for (int y = 0; y < RC; ++y) s += part1[(size_t)y * NN + col];
    c[col] = s;
}

// Pass 2 over A: 9 weighted row-combinations of A.
// v=0: weights c[m] (-> d); v=1..8: weights A[n_s, m] (-> e_s). grid (COLB, RC), block 256
__global__ void k2_rowcomb_part(const float* __restrict__ A, const float* __restrict__ c,
                                float* __restrict__ part2) {
    __shared__ float w[CHUNK][9];
    int col = blockIdx.x * 256 + threadIdx.x;
    int m0 = blockIdx.y * CHUNK;
    for (int idx = threadIdx.x; idx < CHUNK * 9; idx += 256) {
        int j = idx / 9, v = idx % 9;
        w[j][v] = (v == 0) ? c[m0 + j]
                           : A[(size_t)special_row(v - 1) * NN + m0 + j];
    }
    __syncthreads();
    float acc[9] = {0.f, 0.f, 0.f, 0.f, 0.f, 0.f, 0.f, 0.f, 0.f};
    const float* Ap = A + (size_t)m0 * NN + col;
    for (int j = 0; j < CHUNK; ++j) {
        float a = Ap[(size_t)j * NN];
        #pragma unroll
        for (int v = 0; v < 9; ++v) acc[v] += w[j][v] * a;
    }
    #pragma unroll
    for (int v = 0; v < 9; ++v)
        part2[((size_t)blockIdx.y * 9 + v) * NN + col] = acc[v];
}

// reduce -> dvec[9][NN]. grid (COLB, 9), block 256
__global__ void k2_rowcomb_red(const float* __restrict__ part2, float* __restrict__ dvec) {
    int col = blockIdx.x * 256 + threadIdx.x;
    int v = blockIdx.y;
    float s = 0.f;
    for (int y = 0; y < RC; ++y) s += part2[((size_t)y * 9 + v) * NN + col];
    dvec[(size_t)v * NN + col] = s;
}

// Contract x with the 9 vectors: qpart[b][pc][v][f] = sum_{p in chunk} dvec[v][p] * x[b][p][f]
// grid (BB, PC), block 256
__global__ void k3_xcontract(const float* __restrict__ x, const float* __restrict__ dvec,
                             float* __restrict__ qpart) {
    __shared__ float xs[PCH * F_IN];   // 40 KB
    __shared__ float wls[9][PCH];      // 9 KB
    int b = blockIdx.x, p0 = blockIdx.y * PCH;
    const float* xsrc = x + ((size_t)b * NN + p0) * F_IN;
    for (int idx = threadIdx.x; idx < PCH * F_IN; idx += 256) xs[idx] = xsrc[idx];
    for (int idx = threadIdx.x; idx < 9 * PCH; idx += 256) {
        int v = idx / PCH, j = idx % PCH;
        wls[v][j] = dvec[(size_t)v * NN + p0 + j];
    }
    __syncthreads();
    for (int o = threadIdx.x; o < 9 * F_IN; o += 256) {
        int v = o / F_IN, f = o % F_IN;
        float s = 0.f;
        for (int j = 0; j < PCH; ++j) s += wls[v][j] * xs[j * F_IN + f];
        qpart[(((size_t)b * PC + blockIdx.y) * 9 + v) * F_IN + f] = s;
    }
}

// Final epilogue: one block per batch.
__global__ void k4_final(const float* __restrict__ A, const float* __restrict__ c,
                         const float* __restrict__ qpart,
                         const float* __restrict__ W1, const float* __restrict__ b1,
                         const float* __restrict__ W2, const float* __restrict__ b2,
                         const float* __restrict__ cw, const float* __restrict__ cb,
                         const float* __restrict__ fw, const float* __restrict__ fb,
                         float* __restrict__ out) {
    int b = blockIdx.x, tid = threadIdx.x;
    __shared__ float q[9][F_IN];
    __shared__ float red[256];
    __shared__ float sC_s;
    __shared__ float r[8];
    __shared__ float u1[HH];
    __shared__ float T[HH];
    __shared__ float v1[8][HH];
    __shared__ float rowh[8][HH];
    __shared__ float S[KW][HH];
    __shared__ float mu[HH];

    // reduce q over p-chunks
    for (int o = tid; o < 9 * F_IN; o += 256) {
        int v = o / F_IN, f = o % F_IN;
        float s = 0.f;
        for (int pc = 0; pc < PC; ++pc)
            s += qpart[(((size_t)b * PC + pc) * 9 + v) * F_IN + f];
        q[v][f] = s;
    }
    // sC = sum(c)
    {
        float s = 0.f;
        for (int i = tid; i < NN; i += 256) s += c[i];
        red[tid] = s;
        __syncthreads();
        for (int off = 128; off > 0; off >>= 1) {
            if (tid < off) red[tid] += red[tid + off];
            __syncthreads();
        }
        if (tid == 0) sC_s = red[0];
        __syncthreads();
    }
    // r_s = rowsum of the 8 special rows
    {
        int g = tid >> 5, l = tid & 31;
        int n = special_row(g);
        float rs = 0.f;
        for (int j = l; j < NN; j += 32) rs += A[(size_t)n * NN + j];
        red[tid] = rs;
        __syncthreads();
        if (tid < 8) {
            float rr = 0.f;
            for (int j = 0; j < 32; ++j) rr += red[tid * 32 + j];
            r[tid] = rr;
        }
        __syncthreads();
    }
    float sC = sC_s;
    // u1 = q_d @ W1 + sC*b1 ; T = u1 @ W2 + N*b2
    if (tid < HH) {
        float u = 0.f;
        for (int f = 0; f < F_IN; ++f) u += q[0][f] * W1[f * HH + tid];
        u1[tid] = u + sC * b1[tid];
    }
    __syncthreads();
    if (tid < HH) {
        float t = 0.f;
        for (int h = 0; h < HH; ++h) t += u1[h] * W2[h * HH + tid];
        T[tid] = t + (float)NN * b2[tid];
    }
    // boundary rows: v1_s = q_{e_s} @ W1 + r_s*b1 ; rowh_s = v1_s @ W2 + b2
    for (int pass = 0; pass < 2; ++pass) {
        int s4 = (tid >> 6) + pass * 4;
        int h = tid & 63;
        float u = 0.f;
        for (int f = 0; f < F_IN; ++f) u += q[1 + s4][f] * W1[f * HH + h];
        v1[s4][h] = u + r[s4] * b1[h];
    }
    __syncthreads();
    for (int pass = 0; pass < 2; ++pass) {
        int s4 = (tid >> 6) + pass * 4;
        int i = tid & 63;
        float t = 0.f;
        for (int h = 0; h < HH; ++h) t += v1[s4][h] * W2[h * HH + i];
        rowh[s4][i] = t + b2[i];
    }
    __syncthreads();
    // windowed sums S[k][i] and conv+mean+fc
    if (tid < HH) {
        int i = tid;
        for (int k = 0; k < KW; ++k) {
            float sgo = T[i];
            for (int ss = 0; ss < k; ++ss) sgo -= rowh[ss][i];
            for (int ss = k + 4; ss < 8; ++ss) sgo -= rowh[ss][i];
            S[k][i] = sgo;
        }
    }
    __syncthreads();
    if (tid < HH) {
        int o = tid;
        float acc = 0.f;
        for (int i = 0; i < HH; ++i) {
            #pragma unroll
            for (int k = 0; k < KW; ++k)
                acc += cw[(o * HH + i) * KW + k] * S[k][i];
        }
        mu[o] = acc / (float)LL + cb[o];
    }
    __syncthreads();
    if (tid < HH) {
        float contrib = mu[tid] * fw[tid];
        for (int off = 32; off > 0; off >>= 1) contrib += __shfl_down(contrib, off);
        if (tid == 0) out[b] = contrib + fb[0];
    }
}

extern "C" void kernel_launch(void* const* d_in, const int* in_sizes, int n_in,
                              void* d_out, int out_size, void* d_ws, size_t ws_size,
                              hipStream_t stream) {
    const float* x  = (const float*)d_in[0];
    const float* A  = (const float*)d_in[1];
    const float* W1 = (const float*)d_in[2];
    const float* b1 = (const float*)d_in[3];
    const float* W2 = (const float*)d_in[4];
    const float* b2 = (const float*)d_in[5];
    const float* cw = (const float*)d_in[6];
    const float* cb = (const float*)d_in[7];
    const float* fw = (const float*)d_in[8];
    const float* fb = (const float*)d_in[9];
    float* out = (float*)d_out;
    float* ws = (float*)d_ws;

    float* part1 = ws + OFF_P1;
    float* c     = ws + OFF_C;
    float* part2 = ws + OFF_P2;
    float* dvec  = ws + OFF_D;
    float* qpart = ws + OFF_Q;

    k1_colsum_part<<<dim3(COLB, RC), 256, 0, stream>>>(A, part1);
    k1_colsum_red<<<dim3(COLB), 256, 0, stream>>>(part1, c);
    k2_rowcomb_part<<<dim3(COLB, RC), 256, 0, stream>>>(A, c, part2);
    k2_rowcomb_red<<<dim3(COLB, 9), 256, 0, stream>>>(part2, dvec);
    k3_xcontract<<<dim3(BB, PC), 256, 0, stream>>>(x, dvec, qpart);
    k4_final<<<dim3(BB), 256, 0, stream>>>(A, c, qpart, W1, b1, W2, b2, cw, cb, fw, fb, out);
}

// Round 2
// 67.444 us; speedup vs baseline: 1.7179x; 1.7179x over previous
//
#include <hip/hip_runtime.h>

#define NN 4096
#define COL4 (NN / 4)      // 1024 float4 per row
#define BB 8
#define F_IN 40
#define HH 64
#define KW 5
#define LL (NN - KW + 1)   // 4092
#define RC 32              // row chunks for A passes (128 rows each)
#define CHUNK (NN / RC)    // 128
#define PC 16              // p-chunks for x contraction
#define PCH (NN / PC)      // 256

// workspace layout (in floats)
#define OFF_P1 0                          // [RC][NN]      partial colsums
#define OFF_C (OFF_P1 + RC * NN)          // [NN]          colsums c
#define OFF_P2 (OFF_C + NN)               // [RC][9][NN]   partial d/e vectors
#define OFF_D (OFF_P2 + RC * 9 * NN)      // [9][NN]       d, e_0..e_7
#define OFF_Q (OFF_D + 9 * NN)            // [BB][PC][9][F_IN] partial q
#define OFF_M (OFF_Q + BB * PC * 9 * F_IN)// [9][F_IN]     adjoint map
#define OFF_C0 (OFF_M + 9 * F_IN)         // [1]           constant
// total = 1,398,121 floats = 5.59 MB

__device__ __forceinline__ int special_row(int s) { return s < 4 ? s : (NN - 8 + s); }
__device__ __forceinline__ void f4add(float4& a, const float4& b) {
    a.x += b.x; a.y += b.y; a.z += b.z; a.w += b.w;
}
__device__ __forceinline__ void f4fma(float4& a, float w, const float4& b) {
    a.x += w * b.x; a.y += w * b.y; a.z += w * b.z; a.w += w * b.w;
}

// Pass 1 over A: partial column sums. grid (16, RC), block (64,4)
__global__ void k1_colsum_part(const float4* __restrict__ A4, float4* __restrict__ part1) {
    int c4 = blockIdx.x * 64 + threadIdx.x;
    int r0 = blockIdx.y * CHUNK + threadIdx.y * (CHUNK / 4);
    const float4* Ap = A4 + (size_t)r0 * COL4 + c4;
    float4 s = {0.f, 0.f, 0.f, 0.f};
    #pragma unroll 8
    for (int j = 0; j < CHUNK / 4; ++j) f4add(s, Ap[(size_t)j * COL4]);
    __shared__ float4 red[4][64];
    red[threadIdx.y][threadIdx.x] = s;
    __syncthreads();
    if (threadIdx.y == 0) {
        float4 t = red[0][threadIdx.x];
        f4add(t, red[1][threadIdx.x]);
        f4add(t, red[2][threadIdx.x]);
        f4add(t, red[3][threadIdx.x]);
        part1[(size_t)blockIdx.y * COL4 + c4] = t;
    }
}

// reduce partial colsums -> c. grid 4, block 256
__global__ void k1_colsum_red(const float4* __restrict__ part1, float4* __restrict__ c4out) {
    int c4 = blockIdx.x * 256 + threadIdx.x;
    float4 s = {0.f, 0.f, 0.f, 0.f};
    #pragma unroll 8
    for (int y = 0; y < RC; ++y) f4add(s, part1[(size_t)y * COL4 + c4]);
    c4out[c4] = s;
}

// Pass 2 over A: 9 weighted row-combinations. grid (16, RC), block (64,4)
__global__ void k2_rowcomb_part(const float4* __restrict__ A4, const float* __restrict__ A,
                                const float* __restrict__ c, float4* __restrict__ part2) {
    __shared__ float w[9][CHUNK];
    __shared__ float4 red2[4][9][64];   // 36.9 KB
    int tid = threadIdx.y * 64 + threadIdx.x;
    int m0 = blockIdx.y * CHUNK;
    for (int idx = tid; idx < 9 * CHUNK; idx += 256) {
        int v = idx / CHUNK, j = idx % CHUNK;
        w[v][j] = (v == 0) ? c[m0 + j] : A[(size_t)special_row(v - 1) * NN + m0 + j];
    }
    __syncthreads();
    int c4 = blockIdx.x * 64 + threadIdx.x;
    const float4* Ap = A4 + (size_t)(m0 + threadIdx.y * (CHUNK / 4)) * COL4 + c4;
    float4 acc[9];
    #pragma unroll
    for (int v = 0; v < 9; ++v) acc[v] = make_float4(0.f, 0.f, 0.f, 0.f);
    #pragma unroll 4
    for (int j = 0; j < CHUNK / 4; ++j) {
        float4 a = Ap[(size_t)j * COL4];
        int jj = threadIdx.y * (CHUNK / 4) + j;
        #pragma unroll
        for (int v = 0; v < 9; ++v) f4fma(acc[v], w[v][jj], a);
    }
    #pragma unroll
    for (int v = 0; v < 9; ++v) red2[threadIdx.y][v][threadIdx.x] = acc[v];
    __syncthreads();
    if (threadIdx.y == 0) {
        #pragma unroll
        for (int v = 0; v < 9; ++v) {
            float4 t = red2[0][v][threadIdx.x];
            f4add(t, red2[1][v][threadIdx.x]);
            f4add(t, red2[2][v][threadIdx.x]);
            f4add(t, red2[3][v][threadIdx.x]);
            part2[((size_t)blockIdx.y * 9 + v) * COL4 + c4] = t;
        }
    }
}

// reduce -> dvec[9][NN]. grid (4, 9), block 256
__global__ void k2_rowcomb_red(const float4* __restrict__ part2, float4* __restrict__ dvec4) {
    int c4 = blockIdx.x * 256 + threadIdx.x;
    int v = blockIdx.y;
    float4 s = {0.f, 0.f, 0.f, 0.f};
    #pragma unroll 8
    for (int y = 0; y < RC; ++y) f4add(s, part2[((size_t)y * 9 + v) * COL4 + c4]);
    dvec4[(size_t)v * COL4 + c4] = s;
}

// Precompute the affine map q -> out: M[9][F_IN], c0. One block, 256 threads.
__global__ void kM_adjoint(const float4* __restrict__ A4, const float* __restrict__ c,
                           const float* __restrict__ W1, const float* __restrict__ b1,
                           const float* __restrict__ W2, const float* __restrict__ b2,
                           const float* __restrict__ cw, const float* __restrict__ cb,
                           const float* __restrict__ fw, const float* __restrict__ fb,
                           float* __restrict__ Mout, float* __restrict__ c0out) {
    int tid = threadIdx.x;
    int wv = tid >> 6, lane = tid & 63;
    __shared__ float r[8];
    __shared__ float sC_s;
    __shared__ float red[256];
    __shared__ float Xp[4][9][64];
    __shared__ float X[9][64];
    __shared__ float P[9][64];
    __shared__ float bw2[64];

    // r[8]: rowsums of the special rows (one wave per 2 rows, float4, shuffle reduce)
    for (int pass = 0; pass < 2; ++pass) {
        int s = wv + pass * 4;
        const float4* Ar = A4 + (size_t)special_row(s) * COL4;
        float acc = 0.f;
        #pragma unroll 8
        for (int j = lane; j < COL4; j += 64) {
            float4 a = Ar[j];
            acc += a.x + a.y + a.z + a.w;
        }
        for (int off = 32; off > 0; off >>= 1) acc += __shfl_down(acc, off);
        if (lane == 0) r[s] = acc;
    }
    // sC = sum(c)
    {
        const float4* c4 = (const float4*)c;
        float s = 0.f;
        #pragma unroll
        for (int j = tid; j < COL4; j += 256) {
            float4 a = c4[j];
            s += a.x + a.y + a.z + a.w;
        }
        red[tid] = s;
        __syncthreads();
        for (int off = 128; off > 0; off >>= 1) {
            if (tid < off) red[tid] += red[tid + off];
            __syncthreads();
        }
        if (tid == 0) sC_s = red[0];
    }
    // X[0][i]=G[i], X[1+s][i]=H_s[i]: conv-window adjoint coefficients
    {
        int og = tid >> 6, i = tid & 63;
        float accG = 0.f, accH[8] = {0.f,0.f,0.f,0.f,0.f,0.f,0.f,0.f};
        for (int oo = 0; oo < 16; ++oo) {
            int o = og * 16 + oo;
            float f = fw[o];
            const float* cwp = cw + ((size_t)o * HH + i) * KW;
            float w0 = cwp[0], w1 = cwp[1], w2 = cwp[2], w3 = cwp[3], w4 = cwp[4];
            accG += f * (w0 + w1 + w2 + w3 + w4);
            accH[0] += f * (w1 + w2 + w3 + w4);
            accH[1] += f * (w2 + w3 + w4);
            accH[2] += f * (w3 + w4);
            accH[3] += f * w4;
            accH[4] += f * w0;
            accH[5] += f * (w0 + w1);
            accH[6] += f * (w0 + w1 + w2);
            accH[7] += f * (w0 + w1 + w2 + w3);
        }
        Xp[og][0][i] = accG;
        #pragma unroll
        for (int s = 0; s < 8; ++s) Xp[og][1 + s][i] = accH[s];
    }
    __syncthreads();
    for (int t = tid; t < 9 * 64; t += 256) {
        int v = t >> 6, i = t & 63;
        float s = Xp[0][v][i] + Xp[1][v][i] + Xp[2][v][i] + Xp[3][v][i];
        X[v][i] = (v == 0 ? 1.f : -1.f) * s / (float)LL;
    }
    __syncthreads();
    // P[v][h] = sum_i X[v][i] * W2[h,i]
    for (int t = tid; t < 9 * 64; t += 256) {
        int v = t >> 6, h = t & 63;
        const float4* W2r = (const float4*)(W2 + (size_t)h * HH);
        float s = 0.f;
        #pragma unroll 4
        for (int ii = 0; ii < 16; ++ii) {
            float4 a = W2r[ii];
            s += a.x * X[v][ii * 4] + a.y * X[v][ii * 4 + 1]
               + a.z * X[v][ii * 4 + 2] + a.w * X[v][ii * 4 + 3];
        }
        P[v][h] = s;
    }
    // bw2[i] = sum_h b1[h] * W2[h,i]
    if (tid < 64) {
        float s = 0.f;
        for (int h = 0; h < HH; ++h) s += b1[h] * W2[(size_t)h * HH + tid];
        bw2[tid] = s;
    }
    __syncthreads();
    // M[v][f] = sum_h P[v][h] * W1[f,h]
    for (int t = tid; t < 9 * F_IN; t += 256) {
        int v = t / F_IN, f = t % F_IN;
        const float4* W1r = (const float4*)(W1 + (size_t)f * HH);
        float s = 0.f;
        #pragma unroll 4
        for (int hh = 0; hh < 16; ++hh) {
            float4 a = W1r[hh];
            s += a.x * P[v][hh * 4] + a.y * P[v][hh * 4 + 1]
               + a.z * P[v][hh * 4 + 2] + a.w * P[v][hh * 4 + 3];
        }
        Mout[t] = s;
    }
    // c0 = fb + sum_o fw*cb + sum_i X0[i]*(sC*bw2[i]+N*b2[i]) + sum_{s,i} X_{1+s}[i]*(r_s*bw2[i]+b2[i])
    {
        float sC = sC_s;
        float part = 0.f;
        for (int t = tid; t < 9 * 64; t += 256) {
            int v = t >> 6, i = t & 63;
            float base = (v == 0) ? (sC * bw2[i] + (float)NN * b2[i])
                                  : (r[v - 1] * bw2[i] + b2[i]);
            part += X[v][i] * base;
        }
        if (tid < 64) part += fw[tid] * cb[tid];
        red[tid] = part;
        __syncthreads();
        for (int off = 128; off > 0; off >>= 1) {
            if (tid < off) red[tid] += red[tid + off];
            __syncthreads();
        }
        if (tid == 0) c0out[0] = red[0] + fb[0];
    }
}

// Contract x with the 9 vectors. grid (BB, PC), block 256
__global__ void k3_xcontract(const float* __restrict__ x, const float* __restrict__ dvec,
                             float* __restrict__ qpart) {
    __shared__ float xs[PCH * F_IN];   // 40 KB
    __shared__ float wls[9][PCH];      // 9 KB
    int b = blockIdx.x, p0 = blockIdx.y * PCH;
    const float4* xsrc4 = (const float4*)(x + ((size_t)b * NN + p0) * F_IN);
    float4* xs4 = (float4*)xs;
    for (int idx = threadIdx.x; idx < PCH * F_IN / 4; idx += 256) xs4[idx] = xsrc4[idx];
    for (int idx = threadIdx.x; idx < 9 * PCH / 4; idx += 256) {
        int v = idx / (PCH / 4), jj = idx % (PCH / 4);
        ((float4*)&wls[v][0])[jj] = ((const float4*)(dvec + (size_t)v * NN + p0))[jj];
    }
    __syncthreads();
    for (int o = threadIdx.x; o < 9 * F_IN; o += 256) {
        int v = o / F_IN, f = o % F_IN;
        float s = 0.f;
        for (int j = 0; j < PCH; ++j) s += wls[v][j] * xs[j * F_IN + f];
        qpart[(((size_t)b * PC + blockIdx.y) * 9 + v) * F_IN + f] = s;
    }
}

// Final: out[b] = <M, q[b]> + c0. grid BB, block 256
__global__ void k4_final(const float* __restrict__ qpart, const float* __restrict__ M,
                         const float* __restrict__ c0p, float* __restrict__ out) {
    int b = blockIdx.x, tid = threadIdx.x;
    float s = 0.f;
    for (int o = tid; o < 9 * F_IN; o += 256) {
        float qs = 0.f;
        #pragma unroll
        for (int pc = 0; pc < PC; ++pc)
            qs += qpart[(size_t)(b * PC + pc) * (9 * F_IN) + o];
        s += M[o] * qs;
    }
    __shared__ float red[256];
    red[tid] = s;
    __syncthreads();
    for (int off = 128; off > 0; off >>= 1) {
        if (tid < off) red[tid] += red[tid + off];
        __syncthreads();
    }
    if (tid == 0) out[b] = red[0] + c0p[0];
}

extern "C" void kernel_launch(void* const* d_in, const int* in_sizes, int n_in,
                              void* d_out, int out_size, void* d_ws, size_t ws_size,
                              hipStream_t stream) {
    const float* x  = (const float*)d_in[0];
    const float* A  = (const float*)d_in[1];
    const float* W1 = (const float*)d_in[2];
    const float* b1 = (const float*)d_in[3];
    const float* W2 = (const float*)d_in[4];
    const float* b2 = (const float*)d_in[5];
    const float* cw = (const float*)d_in[6];
    const float* cb = (const float*)d_in[7];
    const float* fw = (const float*)d_in[8];
    const float* fb = (const float*)d_in[9];
    float* out = (float*)d_out;
    float* ws = (float*)d_ws;

    float* part1 = ws + OFF_P1;
    float* c     = ws + OFF_C;
    float* part2 = ws + OFF_P2;
    float* dvec  = ws + OFF_D;
    float* qpart = ws + OFF_Q;
    float* Mmat  = ws + OFF_M;
    float* c0p   = ws + OFF_C0;

    const float4* A4 = (const float4*)A;

    k1_colsum_part<<<dim3(16, RC), dim3(64, 4), 0, stream>>>(A4, (float4*)part1);
    k1_colsum_red<<<dim3(4), 256, 0, stream>>>((const float4*)part1, (float4*)c);
    kM_adjoint<<<dim3(1), 256, 0, stream>>>(A4, c, W1, b1, W2, b2, cw, cb, fw, fb, Mmat, c0p);
    k2_rowcomb_part<<<dim3(16, RC), dim3(64, 4), 0, stream>>>(A4, A, c, (float4*)part2);
    k2_rowcomb_red<<<dim3(4, 9), 256, 0, stream>>>((const float4*)part2, (float4*)dvec);
    k3_xcontract<<<dim3(BB, PC), 256, 0, stream>>>(x, dvec, qpart);
    k4_final<<<dim3(BB), 256, 0, stream>>>(qpart, Mmat, c0p, out);
}